// Round 5
// baseline (95.137 us; speedup 1.0000x reference)
//
#include <hip/hip_runtime.h>

// ---------------------------------------------------------------------------
// SpaceTimeStepLookTable, round 5: algebraic fold.
//   out[n,c] = sum_k relu(feats[n,k]) * Wf[c,k]  + dir/t terms + b
//   where Wf = Wproj[:, :128] @ W_mlp   (4 x 37848, fp32, computed per call)
// Packed layout (kp): dense[0,1024) = [f0|f1|time|nb|zeros40]
//                     f2  [1024,5120)   f3 [5120,37888)
// All fp32 — no bf16, no MFMA. Memory-bound streaming gather + 4-ch dot.
// ---------------------------------------------------------------------------

#define N_PTS 2048
#define KP_TOTAL 37888
#define K_ORIG 37848
#define KSPLIT 32
#define KRANGE 1184               // 37888 / 32 = 296 floats/thread-group * 4
#define FOLD_BLOCKS 148           // 148*256 == 37888

// ---------------------------------------------------------------------------
// Kernel 1 (setup): blocks [0,148) fold Wf; blocks [148, 148+2048) prep dense.
// ---------------------------------------------------------------------------
__global__ __launch_bounds__(256) void setup_kernel(
    const float* __restrict__ Wm, const float* __restrict__ Wproj,
    float* __restrict__ Wf,
    const float* __restrict__ pos, const float* __restrict__ t,
    const float* __restrict__ table0, const float* __restrict__ table1,
    const float* __restrict__ ts1, const float* __restrict__ ts2,
    float* __restrict__ dense, int* __restrict__ bases) {

    const int b = blockIdx.x;
    const int tid = threadIdx.x;

    if (b < FOLD_BLOCKS) {
        // ---- fold: Wf[c][kp] = sum_j Wproj[c*132+j] * Wm[j*K_ORIG + k(kp)] ----
        const int kp = b * 256 + tid;    // [0,37888)
        int k; bool valid = true;
        if (kp < 576)        k = kp;                       // f0+f1
        else if (kp < 768)   k = 37440 + (kp - 576);       // time
        else if (kp < 984)   k = 37632 + (kp - 768);       // nb
        else if (kp < 1024)  { k = 0; valid = false; }     // zero pad
        else if (kp < 5120)  k = 576 + (kp - 1024);        // f2
        else                 k = 4672 + (kp - 5120);       // f3
        float a0 = 0.f, a1 = 0.f, a2 = 0.f, a3 = 0.f;
        if (valid) {
            const float* wk = Wm + k;
            #pragma unroll 4
            for (int j = 0; j < 128; ++j) {
                const float w = wk[(size_t)j * K_ORIG];
                a0 = fmaf(Wproj[0 * 132 + j], w, a0);
                a1 = fmaf(Wproj[1 * 132 + j], w, a1);
                a2 = fmaf(Wproj[2 * 132 + j], w, a2);
                a3 = fmaf(Wproj[3 * 132 + j], w, a3);
            }
        }
        Wf[0 * KP_TOTAL + kp] = a0;
        Wf[1 * KP_TOTAL + kp] = a1;
        Wf[2 * KP_TOTAL + kp] = a2;
        Wf[3 * KP_TOTAL + kp] = a3;
        return;
    }

    // ---- prep: materialize dense segment (f0|f1|time|nb|pad) + bases ----
    const int n = b - FOLD_BLOCKS;
    const float px = pos[3 * n], py = pos[3 * n + 1], pz = pos[3 * n + 2];
    const float tv = t[n];
    const int i0 = (int)(px * 127.f), j0 = (int)(py * 127.f), k0 = (int)(pz * 127.f);
    const int i1 = (int)(px * 63.f),  j1 = (int)(py * 63.f),  k1 = (int)(pz * 63.f);
    const int i2 = (int)(px * 31.f),  j2 = (int)(py * 31.f),  k2 = (int)(pz * 31.f);
    const int i3 = (int)(px * 15.f),  j3 = (int)(py * 15.f),  k3 = (int)(pz * 15.f);
    const int ti = (int)(tv * 127.f);

    float* drow = dense + (size_t)n * 1024;

    if (tid < 64)
        drow[tid] = table0[(size_t)(((i0 * 128 + j0) * 128 + k0)) * 64 + tid];
    #pragma unroll
    for (int e = tid; e < 512; e += 256)
        drow[64 + e] = table1[(size_t)(((i1 * 64 + j1) * 64 + k1)) * 512 + e];
    if (tid < 192) {
        const int d = tid >> 6, e = tid & 63;
        const int tw = (ti + d - 1 + 64) & 63;
        drow[576 + tid] = ts1[((size_t)(((i3 * 16 + j3) * 16 + k3)) * 64 + tw) * 64 + e];
    }
    if (tid < 216) {
        const int o = tid >> 2, cc = tid & 3;
        const int dt_ = (o & 1) ? 1 : -1;
        const int rest = o >> 1;
        const int dz_ = rest % 3 - 1;
        const int dy_ = (rest / 3) % 3 - 1;
        const int dx_ = rest / 9 - 1;
        const int x = (i3 + dx_ + 128) & 127;
        const int y = (j3 + dy_ + 128) & 127;
        const int z = (k3 + dz_ + 128) & 127;
        const int w = (ti + dt_ + 128) & 127;
        drow[768 + tid] = ts2[(((((size_t)x * 128 + y) * 128 + z) * 128 + w) * 4) + cc];
    } else if (tid >= 216 && tid < 256) {
        drow[768 + tid] = 0.f;    // kp [984,1024) zero pad
    }
    if (tid == 0) {
        bases[2 * n]     = ((i2 * 32 + j2) * 32 + k2) * 4096;   // f2 row base
        bases[2 * n + 1] = ((i3 * 16 + j3) * 16 + k3) * 32768;  // f3 row base
    }
}

// ---------------------------------------------------------------------------
// Kernel 2: main streaming gather + relu + 4-channel dot, split-K.
// grid (KSPLIT=32, 32) x 256: block = 64 points, K-range 1184.
// Thread layout: p = tid>>2 (point), q = tid&3; thread handles 8 consecutive
// floats per iteration -> the 4 q-threads of a point cover one 128-B line.
// Segment boundaries (1024, 5120) are multiples of 8 -> no intra-run straddle.
// ---------------------------------------------------------------------------
__global__ __launch_bounds__(256) void main_kernel(
    const float* __restrict__ dense, const float* __restrict__ table2,
    const float* __restrict__ table3, const int* __restrict__ bases,
    const float* __restrict__ Wf, float* __restrict__ part) {

    const int ks = blockIdx.x;
    const int mb = blockIdx.y;
    const int tid = threadIdx.x;
    const int p = tid >> 2;
    const int q = tid & 3;
    const int n = mb * 64 + p;

    const float* drow = dense + (size_t)n * 1024;
    const int f2b = bases[2 * n];
    const int f3b = bases[2 * n + 1];
    const int kbase = ks * KRANGE + q * 8;

    float acc0 = 0.f, acc1 = 0.f, acc2 = 0.f, acc3 = 0.f;

    #pragma unroll 2
    for (int i = 0; i < 37; ++i) {
        const int kp = kbase + i * 32;
        const float* src;
        if (kp < 1024)      src = drow + kp;
        else if (kp < 5120) src = table2 + (size_t)f2b + (kp - 1024);
        else                src = table3 + (size_t)f3b + (kp - 5120);
        float4 fa = ((const float4*)src)[0];
        float4 fb = ((const float4*)src)[1];
        fa.x = fmaxf(fa.x, 0.f); fa.y = fmaxf(fa.y, 0.f);
        fa.z = fmaxf(fa.z, 0.f); fa.w = fmaxf(fa.w, 0.f);
        fb.x = fmaxf(fb.x, 0.f); fb.y = fmaxf(fb.y, 0.f);
        fb.z = fmaxf(fb.z, 0.f); fb.w = fmaxf(fb.w, 0.f);

        const float4* w0 = (const float4*)(Wf + 0 * KP_TOTAL + kp);
        const float4* w1 = (const float4*)(Wf + 1 * KP_TOTAL + kp);
        const float4* w2 = (const float4*)(Wf + 2 * KP_TOTAL + kp);
        const float4* w3 = (const float4*)(Wf + 3 * KP_TOTAL + kp);
        float4 wa, wb;
        wa = w0[0]; wb = w0[1];
        acc0 = fmaf(wa.x, fa.x, fmaf(wa.y, fa.y, fmaf(wa.z, fa.z, fmaf(wa.w, fa.w,
               fmaf(wb.x, fb.x, fmaf(wb.y, fb.y, fmaf(wb.z, fb.z, fmaf(wb.w, fb.w, acc0))))))));
        wa = w1[0]; wb = w1[1];
        acc1 = fmaf(wa.x, fa.x, fmaf(wa.y, fa.y, fmaf(wa.z, fa.z, fmaf(wa.w, fa.w,
               fmaf(wb.x, fb.x, fmaf(wb.y, fb.y, fmaf(wb.z, fb.z, fmaf(wb.w, fb.w, acc1))))))));
        wa = w2[0]; wb = w2[1];
        acc2 = fmaf(wa.x, fa.x, fmaf(wa.y, fa.y, fmaf(wa.z, fa.z, fmaf(wa.w, fa.w,
               fmaf(wb.x, fb.x, fmaf(wb.y, fb.y, fmaf(wb.z, fb.z, fmaf(wb.w, fb.w, acc2))))))));
        wa = w3[0]; wb = w3[1];
        acc3 = fmaf(wa.x, fa.x, fmaf(wa.y, fa.y, fmaf(wa.z, fa.z, fmaf(wa.w, fa.w,
               fmaf(wb.x, fb.x, fmaf(wb.y, fb.y, fmaf(wb.z, fb.z, fmaf(wb.w, fb.w, acc3))))))));
    }

    // reduce across the 4 q-lanes of each point (fixed order: deterministic)
    acc0 += __shfl_xor(acc0, 1); acc0 += __shfl_xor(acc0, 2);
    acc1 += __shfl_xor(acc1, 1); acc1 += __shfl_xor(acc1, 2);
    acc2 += __shfl_xor(acc2, 1); acc2 += __shfl_xor(acc2, 2);
    acc3 += __shfl_xor(acc3, 1); acc3 += __shfl_xor(acc3, 2);

    if (q == 0) {
        float4 r; r.x = acc0; r.y = acc1; r.z = acc2; r.w = acc3;
        ((float4*)part)[(size_t)ks * N_PTS + n] = r;
    }
}

// ---------------------------------------------------------------------------
// Kernel 3: reduce split-K partials + dir/t/bias terms -> out.
// grid 32 x 256: n = blockIdx*64 + tid>>2, c = tid&3.
// ---------------------------------------------------------------------------
__global__ __launch_bounds__(256) void reduce_kernel(
    const float* __restrict__ part, const float* __restrict__ dir,
    const float* __restrict__ t, const float* __restrict__ Wproj,
    const float* __restrict__ bproj, float* __restrict__ out) {
    const int tid = threadIdx.x;
    const int n = blockIdx.x * 64 + (tid >> 2);
    const int c = tid & 3;
    float s = 0.f;
    #pragma unroll
    for (int ks = 0; ks < KSPLIT; ++ks)
        s += part[((size_t)ks * N_PTS + n) * 4 + c];
    s += dir[3 * n]     * Wproj[c * 132 + 128];
    s += dir[3 * n + 1] * Wproj[c * 132 + 129];
    s += dir[3 * n + 2] * Wproj[c * 132 + 130];
    s += t[n]           * Wproj[c * 132 + 131];
    s += bproj[c];
    out[n * 4 + c] = s;
}

// ---------------------------------------------------------------------------
extern "C" void kernel_launch(void* const* d_in, const int* in_sizes, int n_in,
                              void* d_out, int out_size, void* d_ws, size_t ws_size,
                              hipStream_t stream) {
    const float* pos    = (const float*)d_in[0];
    const float* dir    = (const float*)d_in[1];
    const float* t      = (const float*)d_in[2];
    const float* table0 = (const float*)d_in[3];
    const float* table1 = (const float*)d_in[4];
    const float* table2 = (const float*)d_in[5];
    const float* table3 = (const float*)d_in[6];
    const float* ts1    = (const float*)d_in[7];
    const float* ts2    = (const float*)d_in[8];
    const float* Wm     = (const float*)d_in[9];
    const float* Wproj  = (const float*)d_in[10];
    const float* bproj  = (const float*)d_in[11];
    float* out = (float*)d_out;

    char* ws = (char*)d_ws;
    float* Wf    = (float*)(ws);                    //   606,208 B (4 x 37888 fp32)
    float* dense = (float*)(ws + 606208);           // 8,388,608 B
    int*   bases = (int*)(ws + 8994816);            //    16,384 B
    float* part  = (float*)(ws + 9011200);          // 1,048,576 B (32 x 2048 x 4)
    // total ws usage: 10,059,776 B

    hipLaunchKernelGGL(setup_kernel, dim3(FOLD_BLOCKS + N_PTS), dim3(256), 0, stream,
                       Wm, Wproj, Wf, pos, t, table0, table1, ts1, ts2, dense, bases);
    hipLaunchKernelGGL(main_kernel, dim3(KSPLIT, 32), dim3(256), 0, stream,
                       dense, table2, table3, bases, Wf, part);
    hipLaunchKernelGGL(reduce_kernel, dim3(32), dim3(256), 0, stream,
                       part, dir, t, Wproj, bproj, out);
}

// Round 6
// 89.711 us; speedup vs baseline: 1.0605x; 1.0605x over previous
//
#include <hip/hip_runtime.h>

// ---------------------------------------------------------------------------
// SpaceTimeStepLookTable, round 6: algebraic fold (round 5) with the fold
// PARALLELIZED. out[n,c] = sum_k relu(feats[n,k]) * Wf[c,k] + dir/t terms + b
// where Wf = Wproj[:, :128] @ W_mlp  (4 x 37888 packed, fp32, per call).
// Packed layout (kp): dense[0,1024) = [f0|f1|time|nb|zeros40]
//                     f2  [1024,5120)   f3 [5120,37888)
// Round-5 failure: fold ran as 148 blocks x 128 serial strided loads
// (0.58 waves/SIMD, ~30 us latency-bound tail). Now: 592 blocks, 4-way
// j-split per block (wave-uniform j -> s_load Wproj), LDS reduce.
// ---------------------------------------------------------------------------

#define N_PTS 2048
#define KP_TOTAL 37888
#define K_ORIG 37848
#define KSPLIT 32
#define KRANGE 1184               // 37888 / 32
#define FOLD_BLOCKS 592           // 592*64 == 37888 kp columns

// ---------------------------------------------------------------------------
// Kernel 1 (setup): blocks [0,592) fold Wf; blocks [592, 592+2048) prep dense.
// ---------------------------------------------------------------------------
__global__ __launch_bounds__(256) void setup_kernel(
    const float* __restrict__ Wm, const float* __restrict__ Wproj,
    float* __restrict__ Wf,
    const float* __restrict__ pos, const float* __restrict__ t,
    const float* __restrict__ table0, const float* __restrict__ table1,
    const float* __restrict__ ts1, const float* __restrict__ ts2,
    float* __restrict__ dense, int* __restrict__ bases) {

    const int b = blockIdx.x;
    const int tid = threadIdx.x;

    if (b < FOLD_BLOCKS) {
        // ---- fold: Wf[c][kp] = sum_j Wproj[c*132+j] * Wm[j*K_ORIG + k(kp)]
        // Block owns 64 kp; wave jq (=tid>>6, wave-uniform) owns j in
        // [jq*32, jq*32+32). 64 lanes = 64 consecutive kp -> coalesced loads.
        __shared__ float red[4][64][4];
        const int kpl = tid & 63;
        const int jq  = tid >> 6;              // == wave id, uniform in wave
        const int kp  = b * 64 + kpl;
        int k; bool valid = true;
        if (kp < 576)        k = kp;                       // f0+f1
        else if (kp < 768)   k = 37440 + (kp - 576);       // time
        else if (kp < 984)   k = 37632 + (kp - 768);       // nb
        else if (kp < 1024)  { k = 0; valid = false; }     // zero pad
        else if (kp < 5120)  k = 576 + (kp - 1024);        // f2
        else                 k = 4672 + (kp - 5120);       // f3
        float a0 = 0.f, a1 = 0.f, a2 = 0.f, a3 = 0.f;
        if (valid) {
            const float* wk = Wm + k;
            const int j0 = jq * 32;
            #pragma unroll
            for (int jj = 0; jj < 32; ++jj) {
                const int j = j0 + jj;
                const float w = wk[(size_t)j * K_ORIG];
                a0 = fmaf(Wproj[0 * 132 + j], w, a0);
                a1 = fmaf(Wproj[1 * 132 + j], w, a1);
                a2 = fmaf(Wproj[2 * 132 + j], w, a2);
                a3 = fmaf(Wproj[3 * 132 + j], w, a3);
            }
        }
        red[jq][kpl][0] = a0; red[jq][kpl][1] = a1;
        red[jq][kpl][2] = a2; red[jq][kpl][3] = a3;
        __syncthreads();
        const int rkpl = tid >> 2, rch = tid & 3;   // 256 threads = 64 kp x 4 ch
        const float s = red[0][rkpl][rch] + red[1][rkpl][rch]
                      + red[2][rkpl][rch] + red[3][rkpl][rch];
        Wf[(size_t)rch * KP_TOTAL + b * 64 + rkpl] = s;
        return;
    }

    // ---- prep: materialize dense segment (f0|f1|time|nb|pad) + bases ----
    const int n = b - FOLD_BLOCKS;
    const float px = pos[3 * n], py = pos[3 * n + 1], pz = pos[3 * n + 2];
    const float tv = t[n];
    const int i0 = (int)(px * 127.f), j0 = (int)(py * 127.f), k0 = (int)(pz * 127.f);
    const int i1 = (int)(px * 63.f),  j1 = (int)(py * 63.f),  k1 = (int)(pz * 63.f);
    const int i2 = (int)(px * 31.f),  j2 = (int)(py * 31.f),  k2 = (int)(pz * 31.f);
    const int i3 = (int)(px * 15.f),  j3 = (int)(py * 15.f),  k3 = (int)(pz * 15.f);
    const int ti = (int)(tv * 127.f);

    float* drow = dense + (size_t)n * 1024;

    if (tid < 64)
        drow[tid] = table0[(size_t)(((i0 * 128 + j0) * 128 + k0)) * 64 + tid];
    #pragma unroll
    for (int e = tid; e < 512; e += 256)
        drow[64 + e] = table1[(size_t)(((i1 * 64 + j1) * 64 + k1)) * 512 + e];
    if (tid < 192) {
        const int d = tid >> 6, e = tid & 63;
        const int tw = (ti + d - 1 + 64) & 63;
        drow[576 + tid] = ts1[((size_t)(((i3 * 16 + j3) * 16 + k3)) * 64 + tw) * 64 + e];
    }
    if (tid < 216) {
        const int o = tid >> 2, cc = tid & 3;
        const int dt_ = (o & 1) ? 1 : -1;
        const int rest = o >> 1;
        const int dz_ = rest % 3 - 1;
        const int dy_ = (rest / 3) % 3 - 1;
        const int dx_ = rest / 9 - 1;
        const int x = (i3 + dx_ + 128) & 127;
        const int y = (j3 + dy_ + 128) & 127;
        const int z = (k3 + dz_ + 128) & 127;
        const int w = (ti + dt_ + 128) & 127;
        drow[768 + tid] = ts2[(((((size_t)x * 128 + y) * 128 + z) * 128 + w) * 4) + cc];
    } else if (tid >= 216 && tid < 256) {
        drow[768 + tid] = 0.f;    // kp [984,1024) zero pad
    }
    if (tid == 0) {
        bases[2 * n]     = ((i2 * 32 + j2) * 32 + k2) * 4096;   // f2 row base
        bases[2 * n + 1] = ((i3 * 16 + j3) * 16 + k3) * 32768;  // f3 row base
    }
}

// ---------------------------------------------------------------------------
// Kernel 2: main streaming gather + relu + 4-channel dot, split-K.
// grid (KSPLIT=32, 32) x 256: block = 64 points, K-range 1184.
// Thread layout: p = tid>>2 (point), q = tid&3; thread handles 8 consecutive
// floats per iteration -> the 4 q-threads of a point cover one 128-B line.
// Wf addresses are wave-uniform (kbase independent of p) -> broadcast loads.
// ---------------------------------------------------------------------------
__global__ __launch_bounds__(256) void main_kernel(
    const float* __restrict__ dense, const float* __restrict__ table2,
    const float* __restrict__ table3, const int* __restrict__ bases,
    const float* __restrict__ Wf, float* __restrict__ part) {

    const int ks = blockIdx.x;
    const int mb = blockIdx.y;
    const int tid = threadIdx.x;
    const int p = tid >> 2;
    const int q = tid & 3;
    const int n = mb * 64 + p;

    const float* drow = dense + (size_t)n * 1024;
    const int f2b = bases[2 * n];
    const int f3b = bases[2 * n + 1];
    const int kbase = ks * KRANGE + q * 8;

    float acc0 = 0.f, acc1 = 0.f, acc2 = 0.f, acc3 = 0.f;

    #pragma unroll 2
    for (int i = 0; i < 37; ++i) {
        const int kp = kbase + i * 32;
        const float* src;
        if (kp < 1024)      src = drow + kp;
        else if (kp < 5120) src = table2 + (size_t)f2b + (kp - 1024);
        else                src = table3 + (size_t)f3b + (kp - 5120);
        float4 fa = ((const float4*)src)[0];
        float4 fb = ((const float4*)src)[1];
        fa.x = fmaxf(fa.x, 0.f); fa.y = fmaxf(fa.y, 0.f);
        fa.z = fmaxf(fa.z, 0.f); fa.w = fmaxf(fa.w, 0.f);
        fb.x = fmaxf(fb.x, 0.f); fb.y = fmaxf(fb.y, 0.f);
        fb.z = fmaxf(fb.z, 0.f); fb.w = fmaxf(fb.w, 0.f);

        const float4* w0 = (const float4*)(Wf + 0 * KP_TOTAL + kp);
        const float4* w1 = (const float4*)(Wf + 1 * KP_TOTAL + kp);
        const float4* w2 = (const float4*)(Wf + 2 * KP_TOTAL + kp);
        const float4* w3 = (const float4*)(Wf + 3 * KP_TOTAL + kp);
        float4 wa, wb;
        wa = w0[0]; wb = w0[1];
        acc0 = fmaf(wa.x, fa.x, fmaf(wa.y, fa.y, fmaf(wa.z, fa.z, fmaf(wa.w, fa.w,
               fmaf(wb.x, fb.x, fmaf(wb.y, fb.y, fmaf(wb.z, fb.z, fmaf(wb.w, fb.w, acc0))))))));
        wa = w1[0]; wb = w1[1];
        acc1 = fmaf(wa.x, fa.x, fmaf(wa.y, fa.y, fmaf(wa.z, fa.z, fmaf(wa.w, fa.w,
               fmaf(wb.x, fb.x, fmaf(wb.y, fb.y, fmaf(wb.z, fb.z, fmaf(wb.w, fb.w, acc1))))))));
        wa = w2[0]; wb = w2[1];
        acc2 = fmaf(wa.x, fa.x, fmaf(wa.y, fa.y, fmaf(wa.z, fa.z, fmaf(wa.w, fa.w,
               fmaf(wb.x, fb.x, fmaf(wb.y, fb.y, fmaf(wb.z, fb.z, fmaf(wb.w, fb.w, acc2))))))));
        wa = w3[0]; wb = w3[1];
        acc3 = fmaf(wa.x, fa.x, fmaf(wa.y, fa.y, fmaf(wa.z, fa.z, fmaf(wa.w, fa.w,
               fmaf(wb.x, fb.x, fmaf(wb.y, fb.y, fmaf(wb.z, fb.z, fmaf(wb.w, fb.w, acc3))))))));
    }

    // reduce across the 4 q-lanes of each point (fixed order: deterministic)
    acc0 += __shfl_xor(acc0, 1); acc0 += __shfl_xor(acc0, 2);
    acc1 += __shfl_xor(acc1, 1); acc1 += __shfl_xor(acc1, 2);
    acc2 += __shfl_xor(acc2, 1); acc2 += __shfl_xor(acc2, 2);
    acc3 += __shfl_xor(acc3, 1); acc3 += __shfl_xor(acc3, 2);

    if (q == 0) {
        float4 r; r.x = acc0; r.y = acc1; r.z = acc2; r.w = acc3;
        ((float4*)part)[(size_t)ks * N_PTS + n] = r;
    }
}

// ---------------------------------------------------------------------------
// Kernel 3: reduce split-K partials + dir/t/bias terms -> out.
// ---------------------------------------------------------------------------
__global__ __launch_bounds__(256) void reduce_kernel(
    const float* __restrict__ part, const float* __restrict__ dir,
    const float* __restrict__ t, const float* __restrict__ Wproj,
    const float* __restrict__ bproj, float* __restrict__ out) {
    const int tid = threadIdx.x;
    const int n = blockIdx.x * 64 + (tid >> 2);
    const int c = tid & 3;
    float s = 0.f;
    #pragma unroll
    for (int ks = 0; ks < KSPLIT; ++ks)
        s += part[((size_t)ks * N_PTS + n) * 4 + c];
    s += dir[3 * n]     * Wproj[c * 132 + 128];
    s += dir[3 * n + 1] * Wproj[c * 132 + 129];
    s += dir[3 * n + 2] * Wproj[c * 132 + 130];
    s += t[n]           * Wproj[c * 132 + 131];
    s += bproj[c];
    out[n * 4 + c] = s;
}

// ---------------------------------------------------------------------------
extern "C" void kernel_launch(void* const* d_in, const int* in_sizes, int n_in,
                              void* d_out, int out_size, void* d_ws, size_t ws_size,
                              hipStream_t stream) {
    const float* pos    = (const float*)d_in[0];
    const float* dir    = (const float*)d_in[1];
    const float* t      = (const float*)d_in[2];
    const float* table0 = (const float*)d_in[3];
    const float* table1 = (const float*)d_in[4];
    const float* table2 = (const float*)d_in[5];
    const float* table3 = (const float*)d_in[6];
    const float* ts1    = (const float*)d_in[7];
    const float* ts2    = (const float*)d_in[8];
    const float* Wm     = (const float*)d_in[9];
    const float* Wproj  = (const float*)d_in[10];
    const float* bproj  = (const float*)d_in[11];
    float* out = (float*)d_out;

    char* ws = (char*)d_ws;
    float* Wf    = (float*)(ws);                    //   606,208 B (4 x 37888 fp32)
    float* dense = (float*)(ws + 606208);           // 8,388,608 B
    int*   bases = (int*)(ws + 8994816);            //    16,384 B
    float* part  = (float*)(ws + 9011200);          // 1,048,576 B (32 x 2048 x 4)
    // total ws usage: 10,059,776 B

    hipLaunchKernelGGL(setup_kernel, dim3(FOLD_BLOCKS + N_PTS), dim3(256), 0, stream,
                       Wm, Wproj, Wf, pos, t, table0, table1, ts1, ts2, dense, bases);
    hipLaunchKernelGGL(main_kernel, dim3(KSPLIT, 32), dim3(256), 0, stream,
                       dense, table2, table3, bases, Wf, part);
    hipLaunchKernelGGL(reduce_kernel, dim3(32), dim3(256), 0, stream,
                       part, dir, t, Wproj, bproj, out);
}

// Round 7
// 72.849 us; speedup vs baseline: 1.3060x; 1.2315x over previous
//
#include <hip/hip_runtime.h>

// ---------------------------------------------------------------------------
// SpaceTimeStepLookTable, round 7: algebraic fold + f3 CELL DEDUP.
//   out[n,c] = dot_dense_f2(n,c) + celldot[cell(n)][c] + dir/t terms + b
//   Wf = Wproj[:, :128] @ W_mlp  (4 x 37888 packed, fp32, per call)
// Packed layout (kp): dense[0,1024) = [f0|f1|time|nb|zeros40]
//                     f2  [1024,5120)   f3 [5120,37888)
// f3 dot depends ONLY on the 16^3 spatial cell (4096 possible, ~1536 unique
// for 2048 uniform points) -> compute once per unique cell (saves ~67 MB of
// the dominant HBM stream + the redundant FMAs).
// ---------------------------------------------------------------------------

#define N_PTS 2048
#define KP_TOTAL 37888
#define K_ORIG 37848
#define KSPLIT_M 20               // dense+f2 split: 5120/20 = 256 floats
#define KS3 4                     // f3 k-quarters of 8192 floats
#define FOLD_BLOCKS 592           // 592*64 == 37888 kp columns

// ---------------------------------------------------------------------------
// Kernel 0: mark unique f3 cells (single block -> no inter-block races).
// list order is atomic-order-dependent but output is invariant to it.
// ---------------------------------------------------------------------------
__global__ __launch_bounds__(1024) void mark_kernel(const float* __restrict__ pos,
                                                    int* __restrict__ list,
                                                    int* __restrict__ count) {
    __shared__ int flags[4096];
    __shared__ int cnt;
    const int tid = threadIdx.x;
    for (int i = tid; i < 4096; i += 1024) flags[i] = 0;
    if (tid == 0) cnt = 0;
    __syncthreads();
    #pragma unroll
    for (int q = 0; q < 2; ++q) {
        const int n = q * 1024 + tid;
        const float px = pos[3 * n], py = pos[3 * n + 1], pz = pos[3 * n + 2];
        const int i3 = (int)(px * 15.f), j3 = (int)(py * 15.f), k3 = (int)(pz * 15.f);
        const int cell = (i3 * 16 + j3) * 16 + k3;
        if (atomicExch(&flags[cell], 1) == 0) {
            const int p = atomicAdd(&cnt, 1);
            list[p] = cell;
        }
    }
    __syncthreads();
    if (tid == 0) count[0] = cnt;
}

// ---------------------------------------------------------------------------
// Kernel 1 (setup): blocks [0,592) fold Wf; blocks [592, 592+2048) prep dense.
// ---------------------------------------------------------------------------
__global__ __launch_bounds__(256) void setup_kernel(
    const float* __restrict__ Wm, const float* __restrict__ Wproj,
    float* __restrict__ Wf,
    const float* __restrict__ pos, const float* __restrict__ t,
    const float* __restrict__ table0, const float* __restrict__ table1,
    const float* __restrict__ ts1, const float* __restrict__ ts2,
    float* __restrict__ dense, int* __restrict__ bases) {

    const int b = blockIdx.x;
    const int tid = threadIdx.x;

    if (b < FOLD_BLOCKS) {
        // ---- fold: Wf[c][kp] = sum_j Wproj[c*132+j] * Wm[j*K_ORIG + k(kp)]
        __shared__ float red[4][64][4];
        const int kpl = tid & 63;
        const int jq  = tid >> 6;              // wave id, uniform in wave
        const int kp  = b * 64 + kpl;
        int k; bool valid = true;
        if (kp < 576)        k = kp;                       // f0+f1
        else if (kp < 768)   k = 37440 + (kp - 576);       // time
        else if (kp < 984)   k = 37632 + (kp - 768);       // nb
        else if (kp < 1024)  { k = 0; valid = false; }     // zero pad
        else if (kp < 5120)  k = 576 + (kp - 1024);        // f2
        else                 k = 4672 + (kp - 5120);       // f3
        float a0 = 0.f, a1 = 0.f, a2 = 0.f, a3 = 0.f;
        if (valid) {
            const float* wk = Wm + k;
            const int j0 = jq * 32;
            #pragma unroll
            for (int jj = 0; jj < 32; ++jj) {
                const int j = j0 + jj;
                const float w = wk[(size_t)j * K_ORIG];
                a0 = fmaf(Wproj[0 * 132 + j], w, a0);
                a1 = fmaf(Wproj[1 * 132 + j], w, a1);
                a2 = fmaf(Wproj[2 * 132 + j], w, a2);
                a3 = fmaf(Wproj[3 * 132 + j], w, a3);
            }
        }
        red[jq][kpl][0] = a0; red[jq][kpl][1] = a1;
        red[jq][kpl][2] = a2; red[jq][kpl][3] = a3;
        __syncthreads();
        const int rkpl = tid >> 2, rch = tid & 3;
        const float s = red[0][rkpl][rch] + red[1][rkpl][rch]
                      + red[2][rkpl][rch] + red[3][rkpl][rch];
        Wf[(size_t)rch * KP_TOTAL + b * 64 + rkpl] = s;
        return;
    }

    // ---- prep: materialize dense segment (f0|f1|time|nb|pad) + bases ----
    const int n = b - FOLD_BLOCKS;
    const float px = pos[3 * n], py = pos[3 * n + 1], pz = pos[3 * n + 2];
    const float tv = t[n];
    const int i0 = (int)(px * 127.f), j0 = (int)(py * 127.f), k0 = (int)(pz * 127.f);
    const int i1 = (int)(px * 63.f),  j1 = (int)(py * 63.f),  k1 = (int)(pz * 63.f);
    const int i2 = (int)(px * 31.f),  j2 = (int)(py * 31.f),  k2 = (int)(pz * 31.f);
    const int i3 = (int)(px * 15.f),  j3 = (int)(py * 15.f),  k3 = (int)(pz * 15.f);
    const int ti = (int)(tv * 127.f);

    float* drow = dense + (size_t)n * 1024;

    if (tid < 64)
        drow[tid] = table0[(size_t)(((i0 * 128 + j0) * 128 + k0)) * 64 + tid];
    #pragma unroll
    for (int e = tid; e < 512; e += 256)
        drow[64 + e] = table1[(size_t)(((i1 * 64 + j1) * 64 + k1)) * 512 + e];
    if (tid < 192) {
        const int d = tid >> 6, e = tid & 63;
        const int tw = (ti + d - 1 + 64) & 63;
        drow[576 + tid] = ts1[((size_t)(((i3 * 16 + j3) * 16 + k3)) * 64 + tw) * 64 + e];
    }
    if (tid < 216) {
        const int o = tid >> 2, cc = tid & 3;
        const int dt_ = (o & 1) ? 1 : -1;
        const int rest = o >> 1;
        const int dz_ = rest % 3 - 1;
        const int dy_ = (rest / 3) % 3 - 1;
        const int dx_ = rest / 9 - 1;
        const int x = (i3 + dx_ + 128) & 127;
        const int y = (j3 + dy_ + 128) & 127;
        const int z = (k3 + dz_ + 128) & 127;
        const int w = (ti + dt_ + 128) & 127;
        drow[768 + tid] = ts2[(((((size_t)x * 128 + y) * 128 + z) * 128 + w) * 4) + cc];
    } else if (tid >= 216 && tid < 256) {
        drow[768 + tid] = 0.f;    // kp [984,1024) zero pad
    }
    if (tid == 0) {
        bases[2 * n]     = ((i2 * 32 + j2) * 32 + k2) * 4096;   // f2 row base
        bases[2 * n + 1] = ((i3 * 16 + j3) * 16 + k3) * 32768;  // f3 row base
    }
}

// ---------------------------------------------------------------------------
// Kernel 2: per-unique-cell f3 dot. grid (KS3=4, 1024) x 256.
// Block (ks, yb) handles cells list[4yb..4yb+4), k-quarter ks (8192 floats).
// Rows are read fully coalesced (1 KB/instr); Wf reused x4 in registers.
// ---------------------------------------------------------------------------
__global__ __launch_bounds__(256) void celldot_kernel(
    const float* __restrict__ table3, const float* __restrict__ Wf,
    const int* __restrict__ list, const int* __restrict__ count,
    float* __restrict__ cellpart) {

    const int cnt = count[0];
    const int yb = blockIdx.y;
    if (yb * 4 >= cnt) return;
    const int ks = blockIdx.x;
    const int tid = threadIdx.x;

    int cell[4]; const float* rowp[4]; bool val[4];
    #pragma unroll
    for (int j = 0; j < 4; ++j) {
        const int idx = yb * 4 + j;
        val[j] = idx < cnt;
        cell[j] = list[val[j] ? idx : 0];
        rowp[j] = table3 + (size_t)cell[j] * 32768;
    }

    const int qbase = ks * 8192;
    const float* wf0 = Wf + (size_t)0 * KP_TOTAL + 5120 + qbase;
    const float* wf1 = Wf + (size_t)1 * KP_TOTAL + 5120 + qbase;
    const float* wf2 = Wf + (size_t)2 * KP_TOTAL + 5120 + qbase;
    const float* wf3 = Wf + (size_t)3 * KP_TOTAL + 5120 + qbase;

    float accv[4][4];
    #pragma unroll
    for (int j = 0; j < 4; ++j)
        #pragma unroll
        for (int c = 0; c < 4; ++c) accv[j][c] = 0.f;

    #pragma unroll 2
    for (int kk = 0; kk < 8; ++kk) {
        const int off = kk * 1024 + tid * 4;
        const float4 w0 = *(const float4*)(wf0 + off);
        const float4 w1 = *(const float4*)(wf1 + off);
        const float4 w2 = *(const float4*)(wf2 + off);
        const float4 w3 = *(const float4*)(wf3 + off);
        #pragma unroll
        for (int j = 0; j < 4; ++j) {
            float4 r = *(const float4*)(rowp[j] + qbase + off);
            r.x = fmaxf(r.x, 0.f); r.y = fmaxf(r.y, 0.f);
            r.z = fmaxf(r.z, 0.f); r.w = fmaxf(r.w, 0.f);
            accv[j][0] = fmaf(r.x, w0.x, fmaf(r.y, w0.y, fmaf(r.z, w0.z, fmaf(r.w, w0.w, accv[j][0]))));
            accv[j][1] = fmaf(r.x, w1.x, fmaf(r.y, w1.y, fmaf(r.z, w1.z, fmaf(r.w, w1.w, accv[j][1]))));
            accv[j][2] = fmaf(r.x, w2.x, fmaf(r.y, w2.y, fmaf(r.z, w2.z, fmaf(r.w, w2.w, accv[j][2]))));
            accv[j][3] = fmaf(r.x, w3.x, fmaf(r.y, w3.y, fmaf(r.z, w3.z, fmaf(r.w, w3.w, accv[j][3]))));
        }
    }

    // wave reduce (fixed shuffle order -> deterministic), then cross-wave LDS
    #pragma unroll
    for (int s = 1; s < 64; s <<= 1)
        #pragma unroll
        for (int j = 0; j < 4; ++j)
            #pragma unroll
            for (int c = 0; c < 4; ++c)
                accv[j][c] += __shfl_xor(accv[j][c], s);

    __shared__ float red[4][16];
    const int wv = tid >> 6, ln = tid & 63;
    if (ln == 0)
        #pragma unroll
        for (int j = 0; j < 4; ++j)
            #pragma unroll
            for (int c = 0; c < 4; ++c)
                red[wv][j * 4 + c] = accv[j][c];
    __syncthreads();
    if (tid < 16) {
        const float s = red[0][tid] + red[1][tid] + red[2][tid] + red[3][tid];
        const int j = tid >> 2, c = tid & 3;
        if (val[j])
            cellpart[((size_t)ks * 4096 + cell[j]) * 4 + c] = s;
    }
}

// ---------------------------------------------------------------------------
// Kernel 3: per-point dense+f2 gather + relu + 4-ch dot, split-K.
// grid (KSPLIT_M=20, 32) x 256: block = 64 points, 256 floats per ks.
// ---------------------------------------------------------------------------
__global__ __launch_bounds__(256) void main_kernel(
    const float* __restrict__ dense, const float* __restrict__ table2,
    const int* __restrict__ bases,
    const float* __restrict__ Wf, float* __restrict__ part) {

    const int ks = blockIdx.x;
    const int mb = blockIdx.y;
    const int tid = threadIdx.x;
    const int p = tid >> 2;
    const int q = tid & 3;
    const int n = mb * 64 + p;

    const float* drow = dense + (size_t)n * 1024;
    const int f2b = bases[2 * n];
    const int kbase = ks * 256 + q * 8;

    float acc0 = 0.f, acc1 = 0.f, acc2 = 0.f, acc3 = 0.f;

    #pragma unroll 2
    for (int i = 0; i < 8; ++i) {
        const int kp = kbase + i * 32;
        const float* src = (kp < 1024) ? (drow + kp)
                                       : (table2 + (size_t)f2b + (kp - 1024));
        float4 fa = ((const float4*)src)[0];
        float4 fb = ((const float4*)src)[1];
        fa.x = fmaxf(fa.x, 0.f); fa.y = fmaxf(fa.y, 0.f);
        fa.z = fmaxf(fa.z, 0.f); fa.w = fmaxf(fa.w, 0.f);
        fb.x = fmaxf(fb.x, 0.f); fb.y = fmaxf(fb.y, 0.f);
        fb.z = fmaxf(fb.z, 0.f); fb.w = fmaxf(fb.w, 0.f);

        const float4* w0 = (const float4*)(Wf + (size_t)0 * KP_TOTAL + kp);
        const float4* w1 = (const float4*)(Wf + (size_t)1 * KP_TOTAL + kp);
        const float4* w2 = (const float4*)(Wf + (size_t)2 * KP_TOTAL + kp);
        const float4* w3 = (const float4*)(Wf + (size_t)3 * KP_TOTAL + kp);
        float4 wa, wb;
        wa = w0[0]; wb = w0[1];
        acc0 = fmaf(wa.x, fa.x, fmaf(wa.y, fa.y, fmaf(wa.z, fa.z, fmaf(wa.w, fa.w,
               fmaf(wb.x, fb.x, fmaf(wb.y, fb.y, fmaf(wb.z, fb.z, fmaf(wb.w, fb.w, acc0))))))));
        wa = w1[0]; wb = w1[1];
        acc1 = fmaf(wa.x, fa.x, fmaf(wa.y, fa.y, fmaf(wa.z, fa.z, fmaf(wa.w, fa.w,
               fmaf(wb.x, fb.x, fmaf(wb.y, fb.y, fmaf(wb.z, fb.z, fmaf(wb.w, fb.w, acc1))))))));
        wa = w2[0]; wb = w2[1];
        acc2 = fmaf(wa.x, fa.x, fmaf(wa.y, fa.y, fmaf(wa.z, fa.z, fmaf(wa.w, fa.w,
               fmaf(wb.x, fb.x, fmaf(wb.y, fb.y, fmaf(wb.z, fb.z, fmaf(wb.w, fb.w, acc2))))))));
        wa = w3[0]; wb = w3[1];
        acc3 = fmaf(wa.x, fa.x, fmaf(wa.y, fa.y, fmaf(wa.z, fa.z, fmaf(wa.w, fa.w,
               fmaf(wb.x, fb.x, fmaf(wb.y, fb.y, fmaf(wb.z, fb.z, fmaf(wb.w, fb.w, acc3))))))));
    }

    acc0 += __shfl_xor(acc0, 1); acc0 += __shfl_xor(acc0, 2);
    acc1 += __shfl_xor(acc1, 1); acc1 += __shfl_xor(acc1, 2);
    acc2 += __shfl_xor(acc2, 1); acc2 += __shfl_xor(acc2, 2);
    acc3 += __shfl_xor(acc3, 1); acc3 += __shfl_xor(acc3, 2);

    if (q == 0) {
        float4 r; r.x = acc0; r.y = acc1; r.z = acc2; r.w = acc3;
        ((float4*)part)[(size_t)ks * N_PTS + n] = r;
    }
}

// ---------------------------------------------------------------------------
// Kernel 4: reduce: dense+f2 partials + cell dot + dir/t/bias -> out.
// ---------------------------------------------------------------------------
__global__ __launch_bounds__(256) void reduce_kernel(
    const float* __restrict__ part, const float* __restrict__ cellpart,
    const int* __restrict__ bases,
    const float* __restrict__ dir, const float* __restrict__ t,
    const float* __restrict__ Wproj, const float* __restrict__ bproj,
    float* __restrict__ out) {
    const int tid = threadIdx.x;
    const int n = blockIdx.x * 64 + (tid >> 2);
    const int c = tid & 3;
    const int cell = bases[2 * n + 1] >> 15;
    float s = 0.f;
    #pragma unroll
    for (int ks = 0; ks < KSPLIT_M; ++ks)
        s += part[((size_t)ks * N_PTS + n) * 4 + c];
    #pragma unroll
    for (int ks = 0; ks < KS3; ++ks)
        s += cellpart[((size_t)ks * 4096 + cell) * 4 + c];
    s += dir[3 * n]     * Wproj[c * 132 + 128];
    s += dir[3 * n + 1] * Wproj[c * 132 + 129];
    s += dir[3 * n + 2] * Wproj[c * 132 + 130];
    s += t[n]           * Wproj[c * 132 + 131];
    s += bproj[c];
    out[n * 4 + c] = s;
}

// ---------------------------------------------------------------------------
extern "C" void kernel_launch(void* const* d_in, const int* in_sizes, int n_in,
                              void* d_out, int out_size, void* d_ws, size_t ws_size,
                              hipStream_t stream) {
    const float* pos    = (const float*)d_in[0];
    const float* dir    = (const float*)d_in[1];
    const float* t      = (const float*)d_in[2];
    const float* table0 = (const float*)d_in[3];
    const float* table1 = (const float*)d_in[4];
    const float* table2 = (const float*)d_in[5];
    const float* table3 = (const float*)d_in[6];
    const float* ts1    = (const float*)d_in[7];
    const float* ts2    = (const float*)d_in[8];
    const float* Wm     = (const float*)d_in[9];
    const float* Wproj  = (const float*)d_in[10];
    const float* bproj  = (const float*)d_in[11];
    float* out = (float*)d_out;

    char* ws = (char*)d_ws;
    float* Wf       = (float*)(ws);                 //   606,208 B
    float* dense    = (float*)(ws + 606208);        // 8,388,608 B
    int*   bases    = (int*)(ws + 8994816);         //    16,384 B
    float* part     = (float*)(ws + 9011200);       //   655,360 B (20 x 2048 x 4)
    float* cellpart = (float*)(ws + 9666560);       //   262,144 B (4 x 4096 x 4)
    int*   list     = (int*)(ws + 9928704);         //    16,384 B
    int*   count    = (int*)(ws + 9945088);         //        64 B
    // total ws usage: 9,945,152 B

    hipLaunchKernelGGL(mark_kernel, dim3(1), dim3(1024), 0, stream, pos, list, count);
    hipLaunchKernelGGL(setup_kernel, dim3(FOLD_BLOCKS + N_PTS), dim3(256), 0, stream,
                       Wm, Wproj, Wf, pos, t, table0, table1, ts1, ts2, dense, bases);
    hipLaunchKernelGGL(celldot_kernel, dim3(KS3, 1024), dim3(256), 0, stream,
                       table3, Wf, list, count, cellpart);
    hipLaunchKernelGGL(main_kernel, dim3(KSPLIT_M, 32), dim3(256), 0, stream,
                       dense, table2, bases, Wf, part);
    hipLaunchKernelGGL(reduce_kernel, dim3(32), dim3(256), 0, stream,
                       part, cellpart, bases, dir, t, Wproj, bproj, out);
}

// Round 8
// 63.187 us; speedup vs baseline: 1.5056x; 1.1529x over previous
//
#include <hip/hip_runtime.h>

// ---------------------------------------------------------------------------
// SpaceTimeStepLookTable, round 8: fold + f3 cell dedup + FULLY FUSED per-point
// kernel (no dense/part buffers).
//   out[n,c] = sum_slots relu(feat4)·Wf4 + celldot[cell(n)][c] + dir/t + b
//   Wf = Wproj[:, :128] @ W_mlp   (4 x 37888 packed, fp32, per call)
// Packed slot map (slot = kp/4): f0 0..15 | f1 16..143 | time 144..191 |
//   nb 192..245 | pad 246..255 | f2 256..1279.  f3 handled by celldot.
// Chain: setup(fold 592 blocks + mark 1 block) -> celldot -> point_kernel.
// ---------------------------------------------------------------------------

#define N_PTS 2048
#define KP_TOTAL 37888
#define K_ORIG 37848
#define KS3 4                     // f3 k-quarters of 8192 floats
#define FOLD_BLOCKS 592           // 592*64 == 37888 kp columns

// ---------------------------------------------------------------------------
// Kernel 1 (setup): blocks [0,592) fold Wf; block 592 marks unique f3 cells.
// ---------------------------------------------------------------------------
__global__ __launch_bounds__(256) void setup_kernel(
    const float* __restrict__ Wm, const float* __restrict__ Wproj,
    float* __restrict__ Wf, const float* __restrict__ pos,
    int* __restrict__ list, int* __restrict__ count) {

    const int b = blockIdx.x;
    const int tid = threadIdx.x;

    if (b < FOLD_BLOCKS) {
        // ---- fold: Wf[c][kp] = sum_j Wproj[c*132+j] * Wm[j*K_ORIG + k(kp)]
        __shared__ float red[4][64][4];
        const int kpl = tid & 63;
        const int jq  = tid >> 6;              // wave id, uniform in wave
        const int kp  = b * 64 + kpl;
        int k; bool valid = true;
        if (kp < 576)        k = kp;                       // f0+f1
        else if (kp < 768)   k = 37440 + (kp - 576);       // time
        else if (kp < 984)   k = 37632 + (kp - 768);       // nb
        else if (kp < 1024)  { k = 0; valid = false; }     // zero pad
        else if (kp < 5120)  k = 576 + (kp - 1024);        // f2
        else                 k = 4672 + (kp - 5120);       // f3
        float a0 = 0.f, a1 = 0.f, a2 = 0.f, a3 = 0.f;
        if (valid) {
            const float* wk = Wm + k;
            const int j0 = jq * 32;
            #pragma unroll
            for (int jj = 0; jj < 32; ++jj) {
                const int j = j0 + jj;
                const float w = wk[(size_t)j * K_ORIG];
                a0 = fmaf(Wproj[0 * 132 + j], w, a0);
                a1 = fmaf(Wproj[1 * 132 + j], w, a1);
                a2 = fmaf(Wproj[2 * 132 + j], w, a2);
                a3 = fmaf(Wproj[3 * 132 + j], w, a3);
            }
        }
        red[jq][kpl][0] = a0; red[jq][kpl][1] = a1;
        red[jq][kpl][2] = a2; red[jq][kpl][3] = a3;
        __syncthreads();
        const int rkpl = tid >> 2, rch = tid & 3;
        const float s = red[0][rkpl][rch] + red[1][rkpl][rch]
                      + red[2][rkpl][rch] + red[3][rkpl][rch];
        Wf[(size_t)rch * KP_TOTAL + b * 64 + rkpl] = s;
        return;
    }

    // ---- mark: unique f3 cells (single block -> no inter-block races) ----
    __shared__ int flags[4096];
    __shared__ int cnt;
    for (int i = tid; i < 4096; i += 256) flags[i] = 0;
    if (tid == 0) cnt = 0;
    __syncthreads();
    #pragma unroll
    for (int q = 0; q < 8; ++q) {
        const int n = q * 256 + tid;
        const float px = pos[3 * n], py = pos[3 * n + 1], pz = pos[3 * n + 2];
        const int i3 = (int)(px * 15.f), j3 = (int)(py * 15.f), k3 = (int)(pz * 15.f);
        const int cell = (i3 * 16 + j3) * 16 + k3;
        if (atomicExch(&flags[cell], 1) == 0) {
            const int p = atomicAdd(&cnt, 1);
            list[p] = cell;
        }
    }
    __syncthreads();
    if (tid == 0) count[0] = cnt;
}

// ---------------------------------------------------------------------------
// Kernel 2: per-unique-cell f3 dot. grid (KS3=4, 512) x 256.
// Block (ks, yb) handles cells list[4yb..4yb+4), k-quarter ks (8192 floats).
// Rows read fully coalesced (1 KB/instr/wave); Wf reused x4 in registers.
// ---------------------------------------------------------------------------
__global__ __launch_bounds__(256) void celldot_kernel(
    const float* __restrict__ table3, const float* __restrict__ Wf,
    const int* __restrict__ list, const int* __restrict__ count,
    float* __restrict__ cellpart) {

    const int cnt = count[0];
    const int yb = blockIdx.y;
    if (yb * 4 >= cnt) return;
    const int ks = blockIdx.x;
    const int tid = threadIdx.x;

    int cell[4]; const float* rowp[4]; bool val[4];
    #pragma unroll
    for (int j = 0; j < 4; ++j) {
        const int idx = yb * 4 + j;
        val[j] = idx < cnt;
        cell[j] = list[val[j] ? idx : 0];
        rowp[j] = table3 + (size_t)cell[j] * 32768;
    }

    const int qbase = ks * 8192;
    const float* wf0 = Wf + (size_t)0 * KP_TOTAL + 5120 + qbase;
    const float* wf1 = Wf + (size_t)1 * KP_TOTAL + 5120 + qbase;
    const float* wf2 = Wf + (size_t)2 * KP_TOTAL + 5120 + qbase;
    const float* wf3 = Wf + (size_t)3 * KP_TOTAL + 5120 + qbase;

    float accv[4][4];
    #pragma unroll
    for (int j = 0; j < 4; ++j)
        #pragma unroll
        for (int c = 0; c < 4; ++c) accv[j][c] = 0.f;

    #pragma unroll 2
    for (int kk = 0; kk < 8; ++kk) {
        const int off = kk * 1024 + tid * 4;
        const float4 w0 = *(const float4*)(wf0 + off);
        const float4 w1 = *(const float4*)(wf1 + off);
        const float4 w2 = *(const float4*)(wf2 + off);
        const float4 w3 = *(const float4*)(wf3 + off);
        #pragma unroll
        for (int j = 0; j < 4; ++j) {
            float4 r = *(const float4*)(rowp[j] + qbase + off);
            r.x = fmaxf(r.x, 0.f); r.y = fmaxf(r.y, 0.f);
            r.z = fmaxf(r.z, 0.f); r.w = fmaxf(r.w, 0.f);
            accv[j][0] = fmaf(r.x, w0.x, fmaf(r.y, w0.y, fmaf(r.z, w0.z, fmaf(r.w, w0.w, accv[j][0]))));
            accv[j][1] = fmaf(r.x, w1.x, fmaf(r.y, w1.y, fmaf(r.z, w1.z, fmaf(r.w, w1.w, accv[j][1]))));
            accv[j][2] = fmaf(r.x, w2.x, fmaf(r.y, w2.y, fmaf(r.z, w2.z, fmaf(r.w, w2.w, accv[j][2]))));
            accv[j][3] = fmaf(r.x, w3.x, fmaf(r.y, w3.y, fmaf(r.z, w3.z, fmaf(r.w, w3.w, accv[j][3]))));
        }
    }

    #pragma unroll
    for (int s = 1; s < 64; s <<= 1)
        #pragma unroll
        for (int j = 0; j < 4; ++j)
            #pragma unroll
            for (int c = 0; c < 4; ++c)
                accv[j][c] += __shfl_xor(accv[j][c], s);

    __shared__ float red[4][16];
    const int wv = tid >> 6, ln = tid & 63;
    if (ln == 0)
        #pragma unroll
        for (int j = 0; j < 4; ++j)
            #pragma unroll
            for (int c = 0; c < 4; ++c)
                red[wv][j * 4 + c] = accv[j][c];
    __syncthreads();
    if (tid < 16) {
        const float s = red[0][tid] + red[1][tid] + red[2][tid] + red[3][tid];
        const int j = tid >> 2, c = tid & 3;
        if (val[j])
            cellpart[((size_t)ks * 4096 + cell[j]) * 4 + c] = s;
    }
}

// ---------------------------------------------------------------------------
// Kernel 3: fused per-point gather + relu + dot + final projection.
// grid 2048 x 256. Thread tid handles slots {tid, 256+tid, ..., 1024+tid};
// slot>=256 is f2 (coalesced float4); slot<256 covers f0/f1/time/nb/pad.
// Wf index = slot*4 for ALL segments (dense+f2); f3 comes from cellpart.
// ---------------------------------------------------------------------------
__global__ __launch_bounds__(256) void point_kernel(
    const float* __restrict__ pos, const float* __restrict__ dir,
    const float* __restrict__ t,
    const float* __restrict__ table0, const float* __restrict__ table1,
    const float* __restrict__ table2,
    const float* __restrict__ ts1, const float* __restrict__ ts2,
    const float* __restrict__ Wf, const float* __restrict__ cellpart,
    const float* __restrict__ Wproj, const float* __restrict__ bproj,
    float* __restrict__ out) {

    const int n = blockIdx.x;
    const int tid = threadIdx.x;

    const float px = pos[3 * n], py = pos[3 * n + 1], pz = pos[3 * n + 2];
    const float tv = t[n];
    const int i0 = (int)(px * 127.f), j0 = (int)(py * 127.f), k0 = (int)(pz * 127.f);
    const int i1 = (int)(px * 63.f),  j1 = (int)(py * 63.f),  k1 = (int)(pz * 63.f);
    const int i2 = (int)(px * 31.f),  j2 = (int)(py * 31.f),  k2 = (int)(pz * 31.f);
    const int i3 = (int)(px * 15.f),  j3 = (int)(py * 15.f),  k3 = (int)(pz * 15.f);
    const int ti = (int)(tv * 127.f);
    const int cell = (i3 * 16 + j3) * 16 + k3;

    const float* f0p = table0 + (size_t)((i0 * 128 + j0) * 128 + k0) * 64;
    const float* f1p = table1 + (size_t)((i1 * 64 + j1) * 64 + k1) * 512;
    const float* f2p = table2 + (size_t)((i2 * 32 + j2) * 32 + k2) * 4096;
    const float* t1p = ts1 + (size_t)cell * 4096;       // + tw*64 + e

    float a0 = 0.f, a1 = 0.f, a2 = 0.f, a3 = 0.f;

    #pragma unroll
    for (int s5 = 0; s5 < 5; ++s5) {
        const int slot = s5 * 256 + tid;
        float4 f;
        bool have = true;
        if (slot >= 256) {
            f = *(const float4*)(f2p + (slot - 256) * 4);
        } else if (slot < 16) {
            f = *(const float4*)(f0p + slot * 4);
        } else if (slot < 144) {
            f = *(const float4*)(f1p + (slot - 16) * 4);
        } else if (slot < 192) {
            const int s2 = slot - 144;
            const int d = s2 >> 4;
            const int e4 = (s2 & 15) * 4;
            const int tw = (ti + d - 1 + 64) & 63;
            f = *(const float4*)(t1p + tw * 64 + e4);
        } else if (slot < 246) {
            const int o = slot - 192;
            const int dt_ = (o & 1) ? 1 : -1;
            const int rest = o >> 1;
            const int dz_ = rest % 3 - 1;
            const int dy_ = (rest / 3) % 3 - 1;
            const int dx_ = rest / 9 - 1;
            const int x = (i3 + dx_ + 128) & 127;
            const int y = (j3 + dy_ + 128) & 127;
            const int z = (k3 + dz_ + 128) & 127;
            const int w = (ti + dt_ + 128) & 127;
            f = *(const float4*)(ts2 + ((size_t)((x * 128 + y) * 128 + z) * 128 + w) * 4);
        } else {
            have = false;
        }
        if (have) {
            f.x = fmaxf(f.x, 0.f); f.y = fmaxf(f.y, 0.f);
            f.z = fmaxf(f.z, 0.f); f.w = fmaxf(f.w, 0.f);
            const int kp = slot * 4;
            const float4 w0 = *(const float4*)(Wf + (size_t)0 * KP_TOTAL + kp);
            const float4 w1 = *(const float4*)(Wf + (size_t)1 * KP_TOTAL + kp);
            const float4 w2 = *(const float4*)(Wf + (size_t)2 * KP_TOTAL + kp);
            const float4 w3 = *(const float4*)(Wf + (size_t)3 * KP_TOTAL + kp);
            a0 = fmaf(f.x, w0.x, fmaf(f.y, w0.y, fmaf(f.z, w0.z, fmaf(f.w, w0.w, a0))));
            a1 = fmaf(f.x, w1.x, fmaf(f.y, w1.y, fmaf(f.z, w1.z, fmaf(f.w, w1.w, a1))));
            a2 = fmaf(f.x, w2.x, fmaf(f.y, w2.y, fmaf(f.z, w2.z, fmaf(f.w, w2.w, a2))));
            a3 = fmaf(f.x, w3.x, fmaf(f.y, w3.y, fmaf(f.z, w3.z, fmaf(f.w, w3.w, a3))));
        }
    }

    // reduce 256 threads -> 4 channels (fixed order: deterministic)
    #pragma unroll
    for (int s = 1; s < 64; s <<= 1) {
        a0 += __shfl_xor(a0, s);
        a1 += __shfl_xor(a1, s);
        a2 += __shfl_xor(a2, s);
        a3 += __shfl_xor(a3, s);
    }
    __shared__ float red[4][4];
    const int wv = tid >> 6, ln = tid & 63;
    if (ln == 0) { red[wv][0] = a0; red[wv][1] = a1; red[wv][2] = a2; red[wv][3] = a3; }
    __syncthreads();
    if (tid < 4) {
        float s = red[0][tid] + red[1][tid] + red[2][tid] + red[3][tid];
        #pragma unroll
        for (int ks = 0; ks < KS3; ++ks)
            s += cellpart[((size_t)ks * 4096 + cell) * 4 + tid];
        s += dir[3 * n]     * Wproj[tid * 132 + 128];
        s += dir[3 * n + 1] * Wproj[tid * 132 + 129];
        s += dir[3 * n + 2] * Wproj[tid * 132 + 130];
        s += tv             * Wproj[tid * 132 + 131];
        s += bproj[tid];
        out[n * 4 + tid] = s;
    }
}

// ---------------------------------------------------------------------------
extern "C" void kernel_launch(void* const* d_in, const int* in_sizes, int n_in,
                              void* d_out, int out_size, void* d_ws, size_t ws_size,
                              hipStream_t stream) {
    const float* pos    = (const float*)d_in[0];
    const float* dir    = (const float*)d_in[1];
    const float* t      = (const float*)d_in[2];
    const float* table0 = (const float*)d_in[3];
    const float* table1 = (const float*)d_in[4];
    const float* table2 = (const float*)d_in[5];
    const float* table3 = (const float*)d_in[6];
    const float* ts1    = (const float*)d_in[7];
    const float* ts2    = (const float*)d_in[8];
    const float* Wm     = (const float*)d_in[9];
    const float* Wproj  = (const float*)d_in[10];
    const float* bproj  = (const float*)d_in[11];
    float* out = (float*)d_out;

    char* ws = (char*)d_ws;
    float* Wf       = (float*)(ws);                 //   606,208 B
    float* cellpart = (float*)(ws + 606208);        //   262,144 B (4 x 4096 x 4)
    int*   list     = (int*)(ws + 868352);          //    16,384 B
    int*   count    = (int*)(ws + 884736);          //        64 B
    // total ws usage: 884,800 B

    hipLaunchKernelGGL(setup_kernel, dim3(FOLD_BLOCKS + 1), dim3(256), 0, stream,
                       Wm, Wproj, Wf, pos, list, count);
    hipLaunchKernelGGL(celldot_kernel, dim3(KS3, 512), dim3(256), 0, stream,
                       table3, Wf, list, count, cellpart);
    hipLaunchKernelGGL(point_kernel, dim3(N_PTS), dim3(256), 0, stream,
                       pos, dir, t, table0, table1, table2, ts1, ts2,
                       Wf, cellpart, Wproj, bproj, out);
}